// Round 1
// baseline (485.111 us; speedup 1.0000x reference)
//
#include <hip/hip_runtime.h>
#include <hip/hip_bf16.h>

#define HH 128
#define HQ 64
#define NPB 8192   // points per batch
#define NT 256     // threads per block

// ---- helpers ----------------------------------------------------------

// pack two f32 -> bf16x2 (round-to-nearest-even)
__device__ __forceinline__ unsigned bfpack2(float lo, float hi) {
    unsigned ul = __float_as_uint(lo);
    unsigned uh = __float_as_uint(hi);
    ul = (ul + 0x7fffu + ((ul >> 16) & 1u)) >> 16;
    uh = (uh + 0x7fffu + ((uh >> 16) & 1u)) & 0xffff0000u;
    return uh | ul;
}

// LayerNorm (+ gamma/beta) + LeakyReLU(0.2) over a per-thread register vector
template<int HO>
__device__ __forceinline__ void ln_lrelu(float* r,
                                         const float* __restrict__ g,
                                         const float* __restrict__ be) {
    float s = 0.f;
#pragma unroll
    for (int j = 0; j < HO; ++j) s += r[j];
    const float mu = s * (1.0f / HO);
    float vs = 0.f;
#pragma unroll
    for (int j = 0; j < HO; ++j) { float d = r[j] - mu; vs = fmaf(d, d, vs); }
    const float rinv = rsqrtf(vs * (1.0f / HO) + 1e-5f);
#pragma unroll
    for (int j = 0; j < HO; ++j) {
        float v = (r[j] - mu) * rinv;
        v = fmaf(v, g[j], be[j]);
        r[j] = fmaxf(v, 0.2f * v);   // leaky relu, slope 0.2
    }
}

// r[j] = bias[j] + sum_{k<128} act_bf16[k] * W[k*HO + j]
// activations read as packed bf16 pairs from LDS (this thread's column)
template<int HO>
__device__ __forceinline__ void matK128(const unsigned* act, int t,
                                        const float* __restrict__ W,
                                        const float* __restrict__ bias,
                                        float* r) {
#pragma unroll
    for (int j = 0; j < HO; ++j) r[j] = bias[j];
#pragma unroll 2
    for (int k2 = 0; k2 < HH / 2; ++k2) {
        const unsigned pk = act[k2 * NT + t];
        const float a0 = __uint_as_float(pk << 16);
        const float a1 = __uint_as_float(pk & 0xffff0000u);
        const float* w0 = W + (2 * k2) * HO;
#pragma unroll
        for (int j = 0; j < HO; ++j) r[j] = fmaf(a0, w0[j], r[j]);
#pragma unroll
        for (int j = 0; j < HO; ++j) r[j] = fmaf(a1, w0[HO + j], r[j]);
    }
}

template<int HO>
__device__ __forceinline__ void storeAct(unsigned* act, int t, const float* r) {
#pragma unroll
    for (int k2 = 0; k2 < HO / 2; ++k2)
        act[k2 * NT + t] = bfpack2(r[2 * k2], r[2 * k2 + 1]);
}

// ---- per-batch bias precompute: ce_contrib[b][j] = cr_b1[j] + cat_emb[cat[b]] . cr_w1[128+ :, j]
__global__ void ce_precompute_kernel(const int* __restrict__ cats,
                                     const float* __restrict__ cat_emb,
                                     const float* __restrict__ cr_w1,
                                     const float* __restrict__ cr_b1,
                                     float* __restrict__ ce_out) {
    const int bb = blockIdx.x;
    const int j  = threadIdx.x;              // 0..127
    const int c  = cats[bb];
    float acc = cr_b1[j];
#pragma unroll 4
    for (int k = 0; k < HH; ++k)
        acc = fmaf(cat_emb[c * HH + k], cr_w1[(HH + k) * HH + j], acc);
    ce_out[bb * HH + j] = acc;
}

// ---- main fused kernel -------------------------------------------------
__global__ __launch_bounds__(NT, 2)
void shape_refine_kernel(
    const float* __restrict__ points, const int* __restrict__ cats,
    const float* __restrict__ pr_w1, const float* __restrict__ pr_b1,
    const float* __restrict__ pr_g1, const float* __restrict__ pr_be1,
    const float* __restrict__ pr_w2, const float* __restrict__ pr_b2,
    const float* __restrict__ pr_g2, const float* __restrict__ pr_be2,
    const float* __restrict__ ce_contrib,
    const float* __restrict__ cr_w1,
    const float* __restrict__ cr_g1, const float* __restrict__ cr_be1,
    const float* __restrict__ cr_w2, const float* __restrict__ cr_b2,
    const float* __restrict__ cr_g2, const float* __restrict__ cr_be2,
    const float* __restrict__ cr_w3, const float* __restrict__ cr_b3,
    const float* __restrict__ sy_w1, const float* __restrict__ sy_b1,
    const float* __restrict__ sy_g1, const float* __restrict__ sy_be1,
    const float* __restrict__ sy_w2, const float* __restrict__ sy_b2,
    const float* __restrict__ sp_w1, const float* __restrict__ sp_b1,
    const float* __restrict__ sp_g1, const float* __restrict__ sp_be1,
    const float* __restrict__ sp_w2, const float* __restrict__ sp_b2,
    const float* __restrict__ sp_g2, const float* __restrict__ sp_be2,
    const float* __restrict__ sp_w3, const float* __restrict__ sp_b3,
    float* __restrict__ out)
{
    __shared__ unsigned act[(HH / 2) * NT];   // 64 KB: packed-bf16 activations, [k2][t]

    const int t = threadIdx.x;
    const int p = blockIdx.x * NT + t;        // global point index
    const int b = blockIdx.x >> 5;            // 8192/256 = 32 blocks per batch (uniform)
    const int cat = __builtin_amdgcn_readfirstlane(cats[b]);

    const float x0 = points[3 * p + 0];
    const float x1 = points[3 * p + 1];
    const float x2 = points[3 * p + 2];

    float r[HH];

    // ---- point refiner: pr1 (3->128) ----
#pragma unroll
    for (int j = 0; j < HH; ++j)
        r[j] = fmaf(x0, pr_w1[j],
               fmaf(x1, pr_w1[HH + j],
               fmaf(x2, pr_w1[2 * HH + j], pr_b1[j])));
    ln_lrelu<HH>(r, pr_g1, pr_be1);
    storeAct<HH>(act, t, r);

    // ---- pr2 (128->128) ----
    matK128<HH>(act, t, pr_w2, pr_b2, r);
    ln_lrelu<HH>(r, pr_g2, pr_be2);
    storeAct<HH>(act, t, r);

    // ---- cr1 (256->128, embedding half folded into per-batch bias) ----
    matK128<HH>(act, t, cr_w1, ce_contrib + b * HH, r);
    ln_lrelu<HH>(r, cr_g1, cr_be1);
    storeAct<HH>(act, t, r);

    // ---- cr2 (128->64) ----
    matK128<HQ>(act, t, cr_w2, cr_b2, r);
    ln_lrelu<HQ>(r, cr_g2, cr_be2);

    // ---- cr3 (64->3) straight from registers ----
    float o0 = cr_b3[0], o1 = cr_b3[1], o2 = cr_b3[2];
#pragma unroll
    for (int k = 0; k < HQ; ++k) {
        o0 = fmaf(r[k], cr_w3[3 * k + 0], o0);
        o1 = fmaf(r[k], cr_w3[3 * k + 1], o1);
        o2 = fmaf(r[k], cr_w3[3 * k + 2], o2);
    }

    // ---- shape prior: sp1 (3->128, per-category weights) ----
    {
        const float* w1c = sp_w1 + cat * 3 * HH;
        const float* b1c = sp_b1 + cat * HH;
#pragma unroll
        for (int j = 0; j < HH; ++j)
            r[j] = fmaf(x0, w1c[j],
                   fmaf(x1, w1c[HH + j],
                   fmaf(x2, w1c[2 * HH + j], b1c[j])));
        ln_lrelu<HH>(r, sp_g1 + cat * HH, sp_be1 + cat * HH);
        storeAct<HH>(act, t, r);
    }

    // ---- sp2 (128->64) ----
    matK128<HQ>(act, t, sp_w2 + cat * HH * HQ, sp_b2 + cat * HQ, r);
    ln_lrelu<HQ>(r, sp_g2 + cat * HQ, sp_be2 + cat * HQ);

    // ---- sp3 (64->3), offsets += 0.5*prior ----
    {
        const float* w3c = sp_w3 + cat * HQ * 3;
        float p0 = sp_b3[cat * 3 + 0], p1 = sp_b3[cat * 3 + 1], p2 = sp_b3[cat * 3 + 2];
#pragma unroll
        for (int k = 0; k < HQ; ++k) {
            p0 = fmaf(r[k], w3c[3 * k + 0], p0);
            p1 = fmaf(r[k], w3c[3 * k + 1], p1);
            p2 = fmaf(r[k], w3c[3 * k + 2], p2);
        }
        o0 = fmaf(0.5f, p0, o0);
        o1 = fmaf(0.5f, p1, o1);
        o2 = fmaf(0.5f, p2, o2);
    }

    // ---- symmetry branch: only for categories 2 and 8 (uniform branch) ----
    if (cat == 2 || cat == 8) {
        const float m0 = -x0, m1 = x1, m2 = x2;   // flip = (-1,1,1)
        float s[HQ];
#pragma unroll
        for (int j = 0; j < HQ; ++j)
            s[j] = fmaf(m0, sy_w1[j],
                   fmaf(m1, sy_w1[HQ + j],
                   fmaf(m2, sy_w1[2 * HQ + j], sy_b1[j])));
        ln_lrelu<HQ>(s, sy_g1, sy_be1);
        float s0 = sy_b2[0], s1 = sy_b2[1], s2 = sy_b2[2];
#pragma unroll
        for (int k = 0; k < HQ; ++k) {
            s0 = fmaf(s[k], sy_w2[3 * k + 0], s0);
            s1 = fmaf(s[k], sy_w2[3 * k + 1], s1);
            s2 = fmaf(s[k], sy_w2[3 * k + 2], s2);
        }
        s0 = -s0;                                  // * flip on output
        o0 = (o0 + s0) * 0.5f;
        o1 = (o1 + s1) * 0.5f;
        o2 = (o2 + s2) * 0.5f;
    }

    out[3 * p + 0] = o0;
    out[3 * p + 1] = o1;
    out[3 * p + 2] = o2;
}

// ---- launch ------------------------------------------------------------
extern "C" void kernel_launch(void* const* d_in, const int* in_sizes, int n_in,
                              void* d_out, int out_size, void* d_ws, size_t ws_size,
                              hipStream_t stream) {
    const float* points  = (const float*)d_in[0];
    const int*   cats    = (const int*)  d_in[1];
    const float* pr_w1   = (const float*)d_in[2];
    const float* pr_b1   = (const float*)d_in[3];
    const float* pr_g1   = (const float*)d_in[4];
    const float* pr_be1  = (const float*)d_in[5];
    const float* pr_w2   = (const float*)d_in[6];
    const float* pr_b2   = (const float*)d_in[7];
    const float* pr_g2   = (const float*)d_in[8];
    const float* pr_be2  = (const float*)d_in[9];
    const float* cat_emb = (const float*)d_in[10];
    const float* cr_w1   = (const float*)d_in[11];
    const float* cr_b1   = (const float*)d_in[12];
    const float* cr_g1   = (const float*)d_in[13];
    const float* cr_be1  = (const float*)d_in[14];
    const float* cr_w2   = (const float*)d_in[15];
    const float* cr_b2   = (const float*)d_in[16];
    const float* cr_g2   = (const float*)d_in[17];
    const float* cr_be2  = (const float*)d_in[18];
    const float* cr_w3   = (const float*)d_in[19];
    const float* cr_b3   = (const float*)d_in[20];
    const float* sy_w1   = (const float*)d_in[21];
    const float* sy_b1   = (const float*)d_in[22];
    const float* sy_g1   = (const float*)d_in[23];
    const float* sy_be1  = (const float*)d_in[24];
    const float* sy_w2   = (const float*)d_in[25];
    const float* sy_b2   = (const float*)d_in[26];
    const float* sp_w1   = (const float*)d_in[27];
    const float* sp_b1   = (const float*)d_in[28];
    const float* sp_g1   = (const float*)d_in[29];
    const float* sp_be1  = (const float*)d_in[30];
    const float* sp_w2   = (const float*)d_in[31];
    const float* sp_b2   = (const float*)d_in[32];
    const float* sp_g2   = (const float*)d_in[33];
    const float* sp_be2  = (const float*)d_in[34];
    const float* sp_w3   = (const float*)d_in[35];
    const float* sp_b3   = (const float*)d_in[36];

    float* ce = (float*)d_ws;                     // 32*128 f32 = 16 KB scratch
    float* out = (float*)d_out;

    ce_precompute_kernel<<<dim3(32), dim3(HH), 0, stream>>>(cats, cat_emb, cr_w1, cr_b1, ce);

    const int total_points = 32 * NPB;            // B*N = 262144
    shape_refine_kernel<<<dim3(total_points / NT), dim3(NT), 0, stream>>>(
        points, cats,
        pr_w1, pr_b1, pr_g1, pr_be1,
        pr_w2, pr_b2, pr_g2, pr_be2,
        ce,
        cr_w1, cr_g1, cr_be1,
        cr_w2, cr_b2, cr_g2, cr_be2,
        cr_w3, cr_b3,
        sy_w1, sy_b1, sy_g1, sy_be1,
        sy_w2, sy_b2,
        sp_w1, sp_b1, sp_g1, sp_be1,
        sp_w2, sp_b2, sp_g2, sp_be2,
        sp_w3, sp_b3,
        out);
}